// Round 1
// baseline (82.156 us; speedup 1.0000x reference)
//
#include <hip/hip_runtime.h>
#include <hip/hip_cooperative_groups.h>

namespace cg = cooperative_groups;

// Problem constants (from setup_inputs): B=256 batches, N=512 keypoints.
#define BATCH 256
#define NPTS  512
#define TPB   256            // 4 waves per block
#define NBLK  (BATCH / 4)    // one wave per batch -> 64 blocks
#define CENTER_X 0.5f

// Fused single cooperative kernel.
// Phase 1: wave w of block g owns batch b = 4*g + w.
//   Per symmetric class k in {0,1,2} with u = x - cx:
//     sum_{i<j} (x_i+x_j-2cx)^2 = (m-2)*su2 + su^2
//     sum_{i<j} (y_i-y_j)^2     = m*sy2 - sy^2
//     pairs                     = m*(m-1)/2
//   Block partial (total, count) -> ws[g], ws[NBLK+g] (agent-scope release).
// Phase 2: grid.sync(); block 0 wave 0 reduces 64 partials, writes mean.
__global__ __launch_bounds__(TPB) void sym_fused(
    const float* __restrict__ kp,   // [B, N, 2]
    const int* __restrict__ cls,    // [B, N]
    float* __restrict__ ws,         // needs 2*NBLK floats
    float* __restrict__ out) {
  const int g = blockIdx.x;
  const int t = threadIdx.x;
  const int wave = t >> 6;
  const int lane = t & 63;
  const int b = g * 4 + wave;      // batch owned by this wave

  float v[15];
#pragma unroll
  for (int i = 0; i < 15; ++i) v[i] = 0.0f;

  const float4* __restrict__ kp4 = (const float4*)kp;  // 2 points per float4
  const int2* __restrict__ cls2 = (const int2*)cls;    // 2 classes per int2

  // 512 points per batch, 64 lanes, 2 points per lane per iter -> 4 iters.
  // Assignment of points to lanes is irrelevant: all sums are symmetric.
#pragma unroll
  for (int i = 0; i < 4; ++i) {
    const int idx = b * (NPTS / 2) + i * 64 + lane;
    const float4 q = kp4[idx];
    const int2 c = cls2[idx];
    const float u0 = q.x - CENTER_X, y0 = q.y;
    const float u1 = q.z - CENTER_X, y1 = q.w;
#pragma unroll
    for (int k = 0; k < 3; ++k) {
      const float s0 = (c.x == k) ? 1.0f : 0.0f;
      const float s1 = (c.y == k) ? 1.0f : 0.0f;
      v[5 * k + 0] += s0 * u0 + s1 * u1;
      v[5 * k + 1] += s0 * (u0 * u0) + s1 * (u1 * u1);
      v[5 * k + 2] += s0 * y0 + s1 * y1;
      v[5 * k + 3] += s0 * (y0 * y0) + s1 * (y1 * y1);
      v[5 * k + 4] += s0 + s1;
    }
  }

  // 64-lane butterfly reduce the 15 per-class sums to lane 0.
#pragma unroll
  for (int off = 32; off >= 1; off >>= 1) {
#pragma unroll
    for (int i = 0; i < 15; ++i) v[i] += __shfl_down(v[i], off, 64);
  }

  __shared__ float lt[4], lc[4];
  if (lane == 0) {
    float total = 0.0f, count = 0.0f;
#pragma unroll
    for (int k = 0; k < 3; ++k) {
      const float su = v[5 * k + 0], su2 = v[5 * k + 1];
      const float sy = v[5 * k + 2], sy2 = v[5 * k + 3];
      const float m = v[5 * k + 4];
      total += (m - 2.0f) * su2 + su * su + m * sy2 - sy * sy;
      count += 0.5f * m * (m - 1.0f);
    }
    lt[wave] = total;
    lc[wave] = count;
  }
  __syncthreads();

  if (t == 0) {
    const float T = lt[0] + lt[1] + lt[2] + lt[3];
    const float C = lc[0] + lc[1] + lc[2] + lc[3];
    // Agent-scope release: partials must be visible across XCDs (G16).
    __hip_atomic_store(&ws[g], T, __ATOMIC_RELEASE, __HIP_MEMORY_SCOPE_AGENT);
    __hip_atomic_store(&ws[NBLK + g], C, __ATOMIC_RELEASE, __HIP_MEMORY_SCOPE_AGENT);
  }

  cg::this_grid().sync();

  // Phase 2: one wave of block 0 reduces the 64 block partials.
  if (g == 0 && t < 64) {
    float T = __hip_atomic_load(&ws[t], __ATOMIC_ACQUIRE, __HIP_MEMORY_SCOPE_AGENT);
    float C = __hip_atomic_load(&ws[NBLK + t], __ATOMIC_ACQUIRE, __HIP_MEMORY_SCOPE_AGENT);
#pragma unroll
    for (int off = 32; off >= 1; off >>= 1) {
      T += __shfl_down(T, off, 64);
      C += __shfl_down(C, off, 64);
    }
    if (t == 0) out[0] = T / fmaxf(C, 1.0f);
  }
}

extern "C" void kernel_launch(void* const* d_in, const int* in_sizes, int n_in,
                              void* d_out, int out_size, void* d_ws, size_t ws_size,
                              hipStream_t stream) {
  const float* kp = (const float*)d_in[0];   // [B, N, 2] float32
  const int* cls = (const int*)d_in[1];      // [B, N] int32
  float* out = (float*)d_out;
  float* ws = (float*)d_ws;                  // needs 2*NBLK floats = 512 B

  void* args[] = {(void*)&kp, (void*)&cls, (void*)&ws, (void*)&out};
  hipLaunchCooperativeKernel((const void*)sym_fused, dim3(NBLK), dim3(TPB),
                             args, 0, stream);
}

// Round 4
// 58.614 us; speedup vs baseline: 1.4016x; 1.4016x over previous
//
#include <hip/hip_runtime.h>

// Problem constants (from setup_inputs): B=256 batches, N=512 keypoints.
#define BATCH 256
#define NPTS  512
#define TPB   256            // 2 points per thread -> one pass
#define CENTER_X 0.5f
// Self-validating publish tag: poison cannot satisfy (a ^ MAGIC) == b unless a
// 64-bit random collision occurs (2^-64); constant-pattern poison gives a == b
// which always fails since MAGIC != 0.
#define MAGIC 0x9E3779B97F4A7C15ULL

// Single-dispatch kernel (no cooperative launch — round 1 showed CG costs +24us).
// Block g == batch b: closed-form per symmetric class k in {0,1,2}, u = x - cx:
//   sum_{i<j} (x_i+x_j-2cx)^2 = (m-2)*su2 + su^2
//   sum_{i<j} (y_i-y_j)^2     = m*sy2 - sy^2
//   pairs                     = m*(m-1)/2
// Publish (T_b, C_b) packed in u64 + XOR-tagged copy (agent-scope release).
// Block 0 finalizes: thread t spin-reads slot t until the tag validates,
// then block-reduces 256 slots and writes the mean.
__global__ __launch_bounds__(TPB) void sym_fused1(
    const float* __restrict__ kp,             // [B, N, 2]
    const int* __restrict__ cls,              // [B, N]
    unsigned long long* __restrict__ ws,      // 2*BATCH u64 = 4 KiB
    float* __restrict__ out) {
  const int b = blockIdx.x;
  const int t = threadIdx.x;
  const int wave = t >> 6;
  const int lane = t & 63;

  // ---- producer phase: this block's batch partial ----
  // 512 points, 256 threads, 2 points/thread, one float4 + one int2 each.
  const float4 q = ((const float4*)kp)[b * (NPTS / 2) + t];
  const int2  c = ((const int2*)cls)[b * (NPTS / 2) + t];
  const float u0 = q.x - CENTER_X, y0 = q.y;
  const float u1 = q.z - CENTER_X, y1 = q.w;

  float v[15];
#pragma unroll
  for (int k = 0; k < 3; ++k) {
    const float s0 = (c.x == k) ? 1.0f : 0.0f;
    const float s1 = (c.y == k) ? 1.0f : 0.0f;
    v[5 * k + 0] = s0 * u0 + s1 * u1;
    v[5 * k + 1] = s0 * (u0 * u0) + s1 * (u1 * u1);
    v[5 * k + 2] = s0 * y0 + s1 * y1;
    v[5 * k + 3] = s0 * (y0 * y0) + s1 * (y1 * y1);
    v[5 * k + 4] = s0 + s1;
  }

  // 64-lane butterfly reduce the 15 per-class sums.
#pragma unroll
  for (int off = 32; off >= 1; off >>= 1) {
#pragma unroll
    for (int i = 0; i < 15; ++i) v[i] += __shfl_down(v[i], off, 64);
  }

  __shared__ float lds[TPB / 64][15];
  if (lane == 0) {
#pragma unroll
    for (int i = 0; i < 15; ++i) lds[wave][i] = v[i];
  }
  __syncthreads();

  if (t == 0) {
    float total = 0.0f, count = 0.0f;
#pragma unroll
    for (int k = 0; k < 3; ++k) {
      float su = 0.f, su2 = 0.f, sy = 0.f, sy2 = 0.f, m = 0.f;
#pragma unroll
      for (int w = 0; w < TPB / 64; ++w) {
        su  += lds[w][5 * k + 0];
        su2 += lds[w][5 * k + 1];
        sy  += lds[w][5 * k + 2];
        sy2 += lds[w][5 * k + 3];
        m   += lds[w][5 * k + 4];
      }
      total += (m - 2.0f) * su2 + su * su + m * sy2 - sy * sy;
      count += 0.5f * m * (m - 1.0f);
    }
    const unsigned long long u =
        ((unsigned long long)__float_as_uint(count) << 32) |
        (unsigned long long)__float_as_uint(total);
    // Store payload first (relaxed), then tag (release): a validated tag
    // guarantees the payload store is visible (agent scope, cross-XCD — G16).
    __hip_atomic_store(&ws[b], u, __ATOMIC_RELAXED, __HIP_MEMORY_SCOPE_AGENT);
    __hip_atomic_store(&ws[BATCH + b], u ^ MAGIC, __ATOMIC_RELEASE,
                       __HIP_MEMORY_SCOPE_AGENT);
  }

  // ---- finalizer phase: block 0 only ----
  if (b == 0) {
    // Thread t spins on slot t. Deadlock-free: 256 blocks always co-resident
    // (256 CUs, >=8 blocks/CU capacity at this register/LDS footprint).
    unsigned long long a, tag;
    do {
      tag = __hip_atomic_load(&ws[BATCH + t], __ATOMIC_ACQUIRE,
                              __HIP_MEMORY_SCOPE_AGENT);
      a   = __hip_atomic_load(&ws[t], __ATOMIC_ACQUIRE,
                              __HIP_MEMORY_SCOPE_AGENT);
    } while ((a ^ MAGIC) != tag);

    float T = __uint_as_float((unsigned)(a & 0xffffffffULL));
    float C = __uint_as_float((unsigned)(a >> 32));

#pragma unroll
    for (int off = 32; off >= 1; off >>= 1) {
      T += __shfl_down(T, off, 64);
      C += __shfl_down(C, off, 64);
    }

    __shared__ float lt[TPB / 64], lc[TPB / 64];
    if (lane == 0) { lt[wave] = T; lc[wave] = C; }
    __syncthreads();

    if (t == 0) {
      float TT = 0.f, CC = 0.f;
#pragma unroll
      for (int w = 0; w < TPB / 64; ++w) { TT += lt[w]; CC += lc[w]; }
      out[0] = TT / fmaxf(CC, 1.0f);
    }
  }
}

extern "C" void kernel_launch(void* const* d_in, const int* in_sizes, int n_in,
                              void* d_out, int out_size, void* d_ws, size_t ws_size,
                              hipStream_t stream) {
  const float* kp = (const float*)d_in[0];   // [B, N, 2] float32
  const int* cls = (const int*)d_in[1];      // [B, N] int32
  float* out = (float*)d_out;
  unsigned long long* ws = (unsigned long long*)d_ws;  // 4 KiB used

  sym_fused1<<<BATCH, TPB, 0, stream>>>(kp, cls, ws, out);
}